// Round 1
// baseline (663.513 us; speedup 1.0000x reference)
//
#include <hip/hip_runtime.h>

// ---------------- problem constants ----------------
#define H_DIM 256
#define E_NUM 524288
#define NN    32768          // B*N nodes
#define K1    544            // 2H+16=528 zero-padded to 17*32
#define K1S   552            // LDS row stride (ushort) for A-tile, ~2-way bank alias
#define K2    512            // 2H
#define K2S   520            // LDS row stride kernel2
#define XS    264            // silu-intermediate row stride (256+8)

typedef unsigned short u16;
typedef unsigned int   u32;
typedef __attribute__((ext_vector_type(8))) short s16x8;
typedef __attribute__((ext_vector_type(4))) float f32x4;
typedef __attribute__((ext_vector_type(4))) unsigned short u16x4;

__device__ __forceinline__ u16 f2b(float x) {
    u32 u = __float_as_uint(x);
    u32 r = (u + 0x7FFFu + ((u >> 16) & 1u)) >> 16;   // RNE; inputs are finite
    return (u16)r;
}

// ---------------- prep: fp32 -> bf16 cast ----------------
__global__ __launch_bounds__(256) void k_cast_bf16(const float* __restrict__ in,
                                                   u16* __restrict__ out, int n4) {
    int i = blockIdx.x * 256 + threadIdx.x;
    if (i >= n4) return;
    float4 v = reinterpret_cast<const float4*>(in)[i];
    u16x4 o;
    o.x = f2b(v.x); o.y = f2b(v.y); o.z = f2b(v.z); o.w = f2b(v.w);
    reinterpret_cast<u16x4*>(out)[i] = o;
}

// ---------------- prep: W[K][N] fp32 -> WT[N][KT] bf16 (zero-padded) ----------------
__global__ __launch_bounds__(256) void k_transpose_bf16(const float* __restrict__ W,
                                                        u16* __restrict__ WT,
                                                        int K, int KT, int N) {
    int idx = blockIdx.x * 256 + threadIdx.x;
    if (idx >= N * KT) return;
    int c = idx / KT, k = idx - c * KT;
    WT[idx] = (k < K) ? f2b(W[(size_t)k * N + c]) : (u16)0;
}

// ---------------- kernel 1: per-edge MLP + atomic scatter-add ----------------
// grid = E/64 blocks, 256 threads (4 waves). Each block: 64 edges x 256 cols.
__global__ __launch_bounds__(256, 2) void k_edges(
    const u16* __restrict__ hbf, const u16* __restrict__ eabf,
    const int* __restrict__ eidx,
    const u16* __restrict__ W1T, const u16* __restrict__ W2T,
    const float* __restrict__ b1, const float* __restrict__ b2,
    float* __restrict__ aggr) {
    __shared__ __align__(16) u16 smem[64 * K1S];   // 70656 B; reused as sX after GEMM1
    __shared__ int sDst[64];
    const int t  = threadIdx.x;
    const int e0 = blockIdx.x * 64;
    const int* srcp = eidx;
    const int* dstp = eidx + E_NUM;

    // ---- stage A tile: [h[src] | h[dst] | edge_attr | 0] in bf16 ----
    {
        const int r = t >> 2, g = t & 3;
        const int e = e0 + r;
        const int s = srcp[e], d = dstp[e];
        if (g == 0) sDst[r] = d;
        const u16* hs = hbf + (size_t)s * H_DIM;
        const u16* hd = hbf + (size_t)d * H_DIM;
        const u16* ea = eabf + (size_t)e * 16;
        u16* rowp = smem + r * K1S;
#pragma unroll
        for (int j = 0; j < 17; ++j) {
            const int c = g + 4 * j;       // 0..67 chunks of 8 bf16 (16B)
            s16x8 v;
            if (c < 32)      v = *reinterpret_cast<const s16x8*>(hs + c * 8);
            else if (c < 64) v = *reinterpret_cast<const s16x8*>(hd + (c - 32) * 8);
            else if (c < 66) v = *reinterpret_cast<const s16x8*>(ea + (c - 64) * 8);
            else             v = s16x8{0, 0, 0, 0, 0, 0, 0, 0};  // zero-pad K 528..543
            *reinterpret_cast<s16x8*>(rowp + c * 8) = v;
        }
    }
    __syncthreads();

    const int lane = t & 63, wv = t >> 6;
    const int l15 = lane & 15, l4 = lane >> 4;
    const int colBase = wv * 64 + l15;
    const f32x4 z4 = {0.f, 0.f, 0.f, 0.f};

    f32x4 acc[4][4];
#pragma unroll
    for (int m = 0; m < 4; ++m)
#pragma unroll
        for (int n = 0; n < 4; ++n) acc[m][n] = z4;

    // ---- GEMM1: (64 x 544) @ W1T^T -> X ----
    {
        const u16* Bb = W1T + (size_t)colBase * K1 + l4 * 8;
        for (int kk = 0; kk < 17; ++kk) {
            s16x8 a[4], b[4];
#pragma unroll
            for (int m = 0; m < 4; ++m)
                a[m] = *reinterpret_cast<const s16x8*>(smem + (m * 16 + l15) * K1S + kk * 32 + l4 * 8);
#pragma unroll
            for (int n = 0; n < 4; ++n)
                b[n] = *reinterpret_cast<const s16x8*>(Bb + n * 16 * K1 + kk * 32);
#pragma unroll
            for (int m = 0; m < 4; ++m)
#pragma unroll
                for (int n = 0; n < 4; ++n)
                    acc[m][n] = __builtin_amdgcn_mfma_f32_16x16x32_bf16(a[m], b[n], acc[m][n], 0, 0, 0);
        }
    }
    __syncthreads();   // all waves done reading A tile

    // ---- epilogue 1: +b1, silu, bf16 -> sX (aliases smem) ----
    {
        u16* sX = smem;
        float b1v[4];
#pragma unroll
        for (int n = 0; n < 4; ++n) b1v[n] = b1[colBase + n * 16];
#pragma unroll
        for (int m = 0; m < 4; ++m)
#pragma unroll
            for (int n = 0; n < 4; ++n)
#pragma unroll
                for (int j = 0; j < 4; ++j) {
                    float x = acc[m][n][j] + b1v[n];
                    float s = x / (1.f + __expf(-x));    // silu
                    sX[(m * 16 + l4 * 4 + j) * XS + colBase + n * 16] = f2b(s);
                }
    }
    __syncthreads();

    // ---- GEMM2: (64 x 256) @ W2T^T -> messages ----
#pragma unroll
    for (int m = 0; m < 4; ++m)
#pragma unroll
        for (int n = 0; n < 4; ++n) acc[m][n] = z4;
    {
        const u16* sX = smem;
        const u16* Bb = W2T + (size_t)colBase * H_DIM + l4 * 8;
        for (int kk = 0; kk < 8; ++kk) {
            s16x8 a[4], b[4];
#pragma unroll
            for (int m = 0; m < 4; ++m)
                a[m] = *reinterpret_cast<const s16x8*>(sX + (m * 16 + l15) * XS + kk * 32 + l4 * 8);
#pragma unroll
            for (int n = 0; n < 4; ++n)
                b[n] = *reinterpret_cast<const s16x8*>(Bb + n * 16 * H_DIM + kk * 32);
#pragma unroll
            for (int m = 0; m < 4; ++m)
#pragma unroll
                for (int n = 0; n < 4; ++n)
                    acc[m][n] = __builtin_amdgcn_mfma_f32_16x16x32_bf16(a[m], b[n], acc[m][n], 0, 0, 0);
        }
    }

    // ---- epilogue 2: +b2, atomic scatter-add by dst ----
    {
        float b2v[4];
#pragma unroll
        for (int n = 0; n < 4; ++n) b2v[n] = b2[colBase + n * 16];
#pragma unroll
        for (int m = 0; m < 4; ++m)
#pragma unroll
            for (int j = 0; j < 4; ++j) {
                const int row = m * 16 + l4 * 4 + j;
                float* outp = aggr + (size_t)sDst[row] * H_DIM + colBase;
#pragma unroll
                for (int n = 0; n < 4; ++n)
                    atomicAdd(outp + n * 16, acc[m][n][j] + b2v[n]);
            }
    }
}

// ---------------- kernel 2: update MLP + residual + LayerNorm + mask ----------------
// grid = NN/64 blocks, 256 threads (4 waves). Each block: 64 nodes x 256 cols.
__global__ __launch_bounds__(256, 2) void k_nodes(
    const float* __restrict__ h,          // original fp32 (residual)
    const u16* __restrict__ hbf,
    const float* __restrict__ aggr,
    const u16* __restrict__ U1T, const u16* __restrict__ U2T,
    const float* __restrict__ c1, const float* __restrict__ c2,
    const float* __restrict__ gamma, const float* __restrict__ beta,
    const float* __restrict__ mask,
    float* __restrict__ out) {
    __shared__ __align__(16) char smemraw[64 * XS * 4];  // 67584 B, multi-purpose
    u16* sA = reinterpret_cast<u16*>(smemraw);           // [64][K2S] bf16
    const int t  = threadIdx.x;
    const int n0 = blockIdx.x * 64;

    // ---- stage A tile: [h | aggr] bf16 ----
    {
        const int r = t >> 2, g = t & 3;
        const int node = n0 + r;
        const u16* hrow = hbf + (size_t)node * H_DIM;
        const float* arow = aggr + (size_t)node * H_DIM;
        u16* rowp = sA + r * K2S;
#pragma unroll
        for (int j = 0; j < 16; ++j) {
            const int c = g + 4 * j;   // 0..63
            if (c < 32) {
                *reinterpret_cast<s16x8*>(rowp + c * 8) =
                    *reinterpret_cast<const s16x8*>(hrow + c * 8);
            } else {
                const int cc = c - 32;
                float4 v0 = *reinterpret_cast<const float4*>(arow + cc * 8);
                float4 v1 = *reinterpret_cast<const float4*>(arow + cc * 8 + 4);
                s16x8 o;
                o[0] = (short)f2b(v0.x); o[1] = (short)f2b(v0.y);
                o[2] = (short)f2b(v0.z); o[3] = (short)f2b(v0.w);
                o[4] = (short)f2b(v1.x); o[5] = (short)f2b(v1.y);
                o[6] = (short)f2b(v1.z); o[7] = (short)f2b(v1.w);
                *reinterpret_cast<s16x8*>(rowp + 256 + cc * 8) = o;
            }
        }
    }
    __syncthreads();

    const int lane = t & 63, wv = t >> 6;
    const int l15 = lane & 15, l4 = lane >> 4;
    const int colBase = wv * 64 + l15;
    const f32x4 z4 = {0.f, 0.f, 0.f, 0.f};

    f32x4 acc[4][4];
#pragma unroll
    for (int m = 0; m < 4; ++m)
#pragma unroll
        for (int n = 0; n < 4; ++n) acc[m][n] = z4;

    // ---- GEMM1b: (64 x 512) @ U1T^T ----
    {
        const u16* Bb = U1T + (size_t)colBase * K2 + l4 * 8;
        for (int kk = 0; kk < 16; ++kk) {
            s16x8 a[4], b[4];
#pragma unroll
            for (int m = 0; m < 4; ++m)
                a[m] = *reinterpret_cast<const s16x8*>(sA + (m * 16 + l15) * K2S + kk * 32 + l4 * 8);
#pragma unroll
            for (int n = 0; n < 4; ++n)
                b[n] = *reinterpret_cast<const s16x8*>(Bb + n * 16 * K2 + kk * 32);
#pragma unroll
            for (int m = 0; m < 4; ++m)
#pragma unroll
                for (int n = 0; n < 4; ++n)
                    acc[m][n] = __builtin_amdgcn_mfma_f32_16x16x32_bf16(a[m], b[n], acc[m][n], 0, 0, 0);
        }
    }
    __syncthreads();

    // ---- epilogue 1: +c1, silu, bf16 -> sX ----
    {
        u16* sX = reinterpret_cast<u16*>(smemraw);
        float c1v[4];
#pragma unroll
        for (int n = 0; n < 4; ++n) c1v[n] = c1[colBase + n * 16];
#pragma unroll
        for (int m = 0; m < 4; ++m)
#pragma unroll
            for (int n = 0; n < 4; ++n)
#pragma unroll
                for (int j = 0; j < 4; ++j) {
                    float x = acc[m][n][j] + c1v[n];
                    float s = x / (1.f + __expf(-x));
                    sX[(m * 16 + l4 * 4 + j) * XS + colBase + n * 16] = f2b(s);
                }
    }
    __syncthreads();

    // ---- GEMM2b: (64 x 256) @ U2T^T ----
#pragma unroll
    for (int m = 0; m < 4; ++m)
#pragma unroll
        for (int n = 0; n < 4; ++n) acc[m][n] = z4;
    {
        const u16* sX = reinterpret_cast<u16*>(smemraw);
        const u16* Bb = U2T + (size_t)colBase * H_DIM + l4 * 8;
        for (int kk = 0; kk < 8; ++kk) {
            s16x8 a[4], b[4];
#pragma unroll
            for (int m = 0; m < 4; ++m)
                a[m] = *reinterpret_cast<const s16x8*>(sX + (m * 16 + l15) * XS + kk * 32 + l4 * 8);
#pragma unroll
            for (int n = 0; n < 4; ++n)
                b[n] = *reinterpret_cast<const s16x8*>(Bb + n * 16 * H_DIM + kk * 32);
#pragma unroll
            for (int m = 0; m < 4; ++m)
#pragma unroll
                for (int n = 0; n < 4; ++n)
                    acc[m][n] = __builtin_amdgcn_mfma_f32_16x16x32_bf16(a[m], b[n], acc[m][n], 0, 0, 0);
        }
    }
    __syncthreads();   // done reading sX before overwriting as fp32

    // ---- epilogue 2: +c2 + residual -> sF (fp32) ----
    {
        float* sF = reinterpret_cast<float*>(smemraw);   // [64][XS]
        float c2v[4];
#pragma unroll
        for (int n = 0; n < 4; ++n) c2v[n] = c2[colBase + n * 16];
#pragma unroll
        for (int m = 0; m < 4; ++m)
#pragma unroll
            for (int n = 0; n < 4; ++n)
#pragma unroll
                for (int j = 0; j < 4; ++j) {
                    const int row = m * 16 + l4 * 4 + j;
                    const float hv = h[(size_t)(n0 + row) * H_DIM + colBase + n * 16];
                    sF[row * XS + colBase + n * 16] = acc[m][n][j] + c2v[n] + hv;
                }
    }
    __syncthreads();

    // ---- LayerNorm + mask + store (4 threads per row) ----
    {
        const float* sF = reinterpret_cast<const float*>(smemraw);
        const int rr = t >> 2, p = t & 3;
        const float* rowf = sF + rr * XS + p * 64;
        float s1 = 0.f, s2 = 0.f;
#pragma unroll
        for (int i = 0; i < 64; ++i) { float v = rowf[i]; s1 += v; s2 += v * v; }
        s1 += __shfl_xor(s1, 1); s1 += __shfl_xor(s1, 2);
        s2 += __shfl_xor(s2, 1); s2 += __shfl_xor(s2, 2);
        const float mu   = s1 * (1.f / 256.f);
        const float var  = s2 * (1.f / 256.f) - mu * mu;
        const float rstd = rsqrtf(var + 1e-5f);
        const int node = n0 + rr;
        const float mk = mask[node];
        float* op = out + (size_t)node * H_DIM + p * 64;
        const float* gp = gamma + p * 64;
        const float* bp = beta + p * 64;
#pragma unroll
        for (int i = 0; i < 64; i += 4) {
            float4 x  = *reinterpret_cast<const float4*>(rowf + i);
            float4 g4 = *reinterpret_cast<const float4*>(gp + i);
            float4 b4 = *reinterpret_cast<const float4*>(bp + i);
            float4 o;
            o.x = (((x.x - mu) * rstd) * g4.x + b4.x) * mk;
            o.y = (((x.y - mu) * rstd) * g4.y + b4.y) * mk;
            o.z = (((x.z - mu) * rstd) * g4.z + b4.z) * mk;
            o.w = (((x.w - mu) * rstd) * g4.w + b4.w) * mk;
            *reinterpret_cast<float4*>(op + i) = o;
        }
    }
}

// ---------------- workspace layout (bytes) ----------------
#define OFF_AGGR  0ull                       // 32768*256*4   = 33554432
#define OFF_HBF   33554432ull                // 32768*256*2   = 16777216
#define OFF_EABF  50331648ull                // 524288*16*2   = 16777216
#define OFF_W1T   67108864ull                // 256*544*2     = 278528
#define OFF_W2T   67387392ull                // 256*256*2     = 131072
#define OFF_U1T   67518464ull                // 256*512*2     = 262144
#define OFF_U2T   67780608ull                // 256*256*2     = 131072

extern "C" void kernel_launch(void* const* d_in, const int* in_sizes, int n_in,
                              void* d_out, int out_size, void* d_ws, size_t ws_size,
                              hipStream_t stream) {
    const float* h     = (const float*)d_in[0];
    const int*   eidx  = (const int*)d_in[1];
    const float* ea    = (const float*)d_in[2];
    const float* mask  = (const float*)d_in[3];
    const float* W1    = (const float*)d_in[4];
    const float* b1    = (const float*)d_in[5];
    const float* W2    = (const float*)d_in[6];
    const float* b2    = (const float*)d_in[7];
    const float* U1    = (const float*)d_in[8];
    const float* c1    = (const float*)d_in[9];
    const float* U2    = (const float*)d_in[10];
    const float* c2    = (const float*)d_in[11];
    const float* gamma = (const float*)d_in[12];
    const float* beta  = (const float*)d_in[13];
    float* out = (float*)d_out;
    char*  ws  = (char*)d_ws;

    float* aggr = (float*)(ws + OFF_AGGR);
    u16* hbf  = (u16*)(ws + OFF_HBF);
    u16* eabf = (u16*)(ws + OFF_EABF);
    u16* W1T  = (u16*)(ws + OFF_W1T);
    u16* W2T  = (u16*)(ws + OFF_W2T);
    u16* U1T  = (u16*)(ws + OFF_U1T);
    u16* U2T  = (u16*)(ws + OFF_U2T);

    hipMemsetAsync(aggr, 0, (size_t)NN * H_DIM * sizeof(float), stream);

    k_cast_bf16<<<8192, 256, 0, stream>>>(h,  hbf,  (NN * H_DIM) / 4);
    k_cast_bf16<<<8192, 256, 0, stream>>>(ea, eabf, (E_NUM * 16) / 4);
    k_transpose_bf16<<<(256 * K1 + 255) / 256, 256, 0, stream>>>(W1, W1T, 528, K1, H_DIM);
    k_transpose_bf16<<<(256 * 256 + 255) / 256, 256, 0, stream>>>(W2, W2T, 256, 256, H_DIM);
    k_transpose_bf16<<<(256 * K2 + 255) / 256, 256, 0, stream>>>(U1, U1T, 512, K2, H_DIM);
    k_transpose_bf16<<<(256 * 256 + 255) / 256, 256, 0, stream>>>(U2, U2T, 256, 256, H_DIM);

    k_edges<<<E_NUM / 64, 256, 0, stream>>>(hbf, eabf, eidx, W1T, W2T, b1, b2, aggr);
    k_nodes<<<NN / 64, 256, 0, stream>>>(h, hbf, aggr, U1T, U2T, c1, c2, gamma, beta, mask, out);
}